// Round 1
// baseline (230.742 us; speedup 1.0000x reference)
//
#include <hip/hip_runtime.h>

// Discrete Laguerre filterbank tap recursion as a PARALLEL SCAN.
//   out[0] = sr*p[0] + s1mr*x
//   out[i] = sr*out[i-1] + (sr*p[i] - p[i-1])     (first-order linear)
//
// Layout: 8 lanes per row, 4 taps per lane (one float4) -> perfectly
// coalesced 16B/lane loads+stores, no LDS tiles, no barriers.
// Scan = in-lane serial (4 elems) + 3-step Kogge-Stone across the 8-lane
// group (width-8 shuffles) with ratios sr^4, sr^8, sr^16.
//
// THIS REVISION (MLP): each thread owns KCH=4 float4 chunks at
// tid + k*nthreads. All 4 loads are issued before any compute, giving 4
// outstanding 16B loads per thread instead of 1 — the previous version's
// single load followed by a ~250-cycle serial shuffle chain left the
// memory pipes idle (~3.9 TB/s effective vs 6.3 TB/s copy ceiling).
// Streaming traffic uses nontemporal hints (no reuse, 128 MB >> 32 MB L2).

#define TAPS 32
#define KCH 4

typedef float f32x4 __attribute__((ext_vector_type(4)));

__global__ __launch_bounds__(256) void laguerre_kernel(
    const float* __restrict__ input_now,
    const float* __restrict__ output_prev,
    const float* __restrict__ relax,
    float* __restrict__ out,
    int nrows, int nthreads)
{
    const int tid = blockIdx.x * blockDim.x + threadIdx.x;
    const int g   = tid & 7;       // lane's position within its 8-lane row group

    const float rr   = relax[0];
    const float sr   = sqrtf(rr);
    const float s1mr = sqrtf(1.0f - rr);
    const float sr2  = sr * sr;
    const float sr3  = sr2 * sr;
    const float a    = sr2 * sr2;  // sr^4
    const float a2   = a * a;      // sr^8
    const float a4   = a2 * a2;    // sr^16

    // ---- phase 1: issue ALL loads (4 outstanding 16B loads / thread) ----
    f32x4 pv[KCH];
    float xv[KCH];
    int   idx[KCH];
    bool  ok[KCH];

#pragma unroll
    for (int k = 0; k < KCH; ++k) {
        idx[k] = tid + k * nthreads;          // nthreads % 8 == 0 -> same g
        const int row = idx[k] >> 3;
        ok[k] = (row < nrows);
        pv[k] = (f32x4){0.f, 0.f, 0.f, 0.f};
        xv[k] = 0.f;
        if (ok[k]) {
            pv[k] = __builtin_nontemporal_load(
                reinterpret_cast<const f32x4*>(output_prev) + idx[k]);
            xv[k] = input_now[row];           // same addr across the 8-group
        }
    }

    // ---- phase 2: 4 independent scan chains + stores ----
#pragma unroll
    for (int k = 0; k < KCH; ++k) {
        const f32x4 p = pv[k];
        const float x = xv[k];

        // p[4g-1] from the previous lane (undefined for g==0, masked below)
        const float prevlast = __shfl_up(p.w, 1, 8);

        // e terms
        const float e0 = (g == 0) ? fmaf(sr, p.x, s1mr * x)
                                  : fmaf(sr, p.x, -prevlast);
        const float e1 = fmaf(sr, p.y, -p.x);
        const float e2 = fmaf(sr, p.z, -p.y);
        const float e3 = fmaf(sr, p.w, -p.z);

        // in-lane serial scan (assumes zero incoming)
        const float w0 = e0;
        const float w1 = fmaf(sr, w0, e1);
        const float w2 = fmaf(sr, w1, e2);
        const float w3 = fmaf(sr, w2, e3);

        // cross-lane Kogge-Stone on lane totals, ratio sr^4 per lane
        float t = w3;
        float u;
        u = __shfl_up(t, 1, 8); t = (g >= 1) ? fmaf(a,  u, t) : t;
        u = __shfl_up(t, 2, 8); t = (g >= 2) ? fmaf(a2, u, t) : t;
        u = __shfl_up(t, 4, 8); t = (g >= 4) ? fmaf(a4, u, t) : t;

        // incoming accumulated value y[4g-1] = previous lane's scanned total
        float inc = __shfl_up(t, 1, 8);
        inc = (g >= 1) ? inc : 0.0f;

        // fix up: y[4g+m] = w_m + sr^(m+1) * inc
        f32x4 yv;
        yv.x = fmaf(sr,  inc, w0);
        yv.y = fmaf(sr2, inc, w1);
        yv.z = fmaf(sr3, inc, w2);
        yv.w = fmaf(a,   inc, w3);

        if (ok[k]) {
            __builtin_nontemporal_store(
                yv, reinterpret_cast<f32x4*>(out) + idx[k]);
        }
    }
}

extern "C" void kernel_launch(void* const* d_in, const int* in_sizes, int n_in,
                              void* d_out, int out_size, void* d_ws, size_t ws_size,
                              hipStream_t stream) {
    const float* input_now   = (const float*)d_in[0];  // [B, 1]
    const float* output_prev = (const float*)d_in[1];  // [B, TAPS]
    const float* relax       = (const float*)d_in[2];  // [1]
    float* out = (float*)d_out;                        // [B, TAPS]

    int nrows = in_sizes[0];                           // B
    // Each thread covers KCH chunks at stride nthreads; keep nthreads a
    // multiple of 8 so every chunk keeps the same in-group lane position g.
    int rows_per_pass = (nrows + KCH - 1) / KCH;
    long long nthreads = (long long)rows_per_pass * 8;
    int block = 256;
    long long grid = (nthreads + block - 1) / block;
    laguerre_kernel<<<(int)grid, block, 0, stream>>>(
        input_now, output_prev, relax, out, nrows, (int)nthreads);
}

// Round 2
// 225.717 us; speedup vs baseline: 1.0223x; 1.0223x over previous
//
#include <hip/hip_runtime.h>

// Discrete Laguerre filterbank tap recursion as a PARALLEL SCAN.
//   out[0] = sr*p[0] + s1mr*x
//   out[i] = sr*out[i-1] + (sr*p[i] - p[i-1])     (first-order linear)
//
// Layout: 8 lanes per row, 4 taps per lane (one float4). Lane tid's float4
// sits at base + 16*tid -> loads AND stores perfectly coalesced, no LDS
// tiles, no barriers. Scan = in-lane serial (4 elems) + 3-step Kogge-Stone
// across the 8-lane group with ratios sr^4, sr^8, sr^16.
//
// THIS REVISION: KCH reverted to 1 (round-1 A/B: KCH=4 batching was
// neutral-to-worse — TLP already saturates VMEM). All 5 cross-lane moves
// switched from __shfl_up (ds_bpermute_b32: LDS pipe, ~30-40 cyc each,
// 3 serial on the critical path) to row_shr DPP (pure VALU, ~4 cyc).
// This is exact, not approximate: every shuffle consumer is already
// predicated on g>=N / g==0, so the cross-8-group leakage at lanes 8k
// (row_shr works on 16-lane rows) lands only in masked-off positions.
// Streams keep nontemporal hints (no reuse; 128 MB >> 32 MB L2).

#define TAPS 32

typedef float f32x4 __attribute__((ext_vector_type(4)));

template<int N>
__device__ __forceinline__ float dpp_shr(float v) {
    // row_shr:N within 16-lane rows; out-of-row lanes keep old (=0).
    // Safe ONLY because every consumer masks lanes with g < N.
    int r = __builtin_amdgcn_update_dpp(
        0, __float_as_int(v), 0x110 | N, 0xF, 0xF, false);
    return __int_as_float(r);
}

__global__ __launch_bounds__(256) void laguerre_kernel(
    const float* __restrict__ input_now,
    const float* __restrict__ output_prev,
    const float* __restrict__ relax,
    float* __restrict__ out,
    int nrows)
{
    const int tid = blockIdx.x * blockDim.x + threadIdx.x;
    const int row = tid >> 3;      // 8 lanes per row
    const int g   = tid & 7;       // lane's position within the row group
    if (row >= nrows) return;

    const float rr   = relax[0];
    const float sr   = sqrtf(rr);
    const float s1mr = sqrtf(1.0f - rr);

    // taps [4g .. 4g+3] of this row — contiguous float4 at index tid
    const f32x4 pv = __builtin_nontemporal_load(
        reinterpret_cast<const f32x4*>(output_prev) + tid);
    const float x = input_now[row];   // broadcast within each 8-lane group

    // p[4g-1] from the previous lane (garbage for g==0, masked below)
    const float prevlast = dpp_shr<1>(pv.w);

    // e terms
    const float e0 = (g == 0) ? fmaf(sr, pv.x, s1mr * x)
                              : fmaf(sr, pv.x, -prevlast);
    const float e1 = fmaf(sr, pv.y, -pv.x);
    const float e2 = fmaf(sr, pv.z, -pv.y);
    const float e3 = fmaf(sr, pv.w, -pv.z);

    // in-lane serial scan (assumes zero incoming)
    const float w0 = e0;
    const float w1 = fmaf(sr, w0, e1);
    const float w2 = fmaf(sr, w1, e2);
    const float w3 = fmaf(sr, w2, e3);

    // cross-lane Kogge-Stone on the lane totals, ratio a = sr^4 per lane
    const float sr2 = sr * sr;
    const float sr3 = sr2 * sr;
    const float a   = sr2 * sr2;   // sr^4
    const float a2  = a * a;       // sr^8
    const float a4  = a2 * a2;     // sr^16

    float t = w3;
    float u;
    u = dpp_shr<1>(t); t = (g >= 1) ? fmaf(a,  u, t) : t;
    u = dpp_shr<2>(t); t = (g >= 2) ? fmaf(a2, u, t) : t;
    u = dpp_shr<4>(t); t = (g >= 4) ? fmaf(a4, u, t) : t;

    // incoming accumulated value y[4g-1] = previous lane's scanned total
    float inc = dpp_shr<1>(t);
    inc = (g >= 1) ? inc : 0.0f;

    // fix up: y[4g+m] = w_m + sr^(m+1) * inc
    f32x4 yv;
    yv.x = fmaf(sr,  inc, w0);
    yv.y = fmaf(sr2, inc, w1);
    yv.z = fmaf(sr3, inc, w2);
    yv.w = fmaf(a,   inc, w3);

    __builtin_nontemporal_store(yv, reinterpret_cast<f32x4*>(out) + tid);
}

extern "C" void kernel_launch(void* const* d_in, const int* in_sizes, int n_in,
                              void* d_out, int out_size, void* d_ws, size_t ws_size,
                              hipStream_t stream) {
    const float* input_now   = (const float*)d_in[0];  // [B, 1]
    const float* output_prev = (const float*)d_in[1];  // [B, TAPS]
    const float* relax       = (const float*)d_in[2];  // [1]
    float* out = (float*)d_out;                        // [B, TAPS]

    int nrows = in_sizes[0];                  // B
    long long threads = (long long)nrows * 8; // 8 lanes per row
    int block = 256;
    long long grid = (threads + block - 1) / block;
    laguerre_kernel<<<(int)grid, block, 0, stream>>>(input_now, output_prev, relax, out, nrows);
}